// Round 2
// baseline (365.578 us; speedup 1.0000x reference)
//
#include <hip/hip_runtime.h>
#include <hip/hip_bf16.h>

#define N_NODES 10000
#define N_EDGES 640000
#define F_IN 128
#define H1 64
#define H2 32
#define N_CLASSES 16

// ---------- degree count ----------
__global__ void k_deg(const int* __restrict__ dst, int* __restrict__ degInt) {
    int e = blockIdx.x * blockDim.x + threadIdx.x;
    if (e < N_EDGES) atomicAdd(&degInt[dst[e]], 1);
}

__global__ void k_dinv(const int* __restrict__ degInt, float* __restrict__ dinv) {
    int v = blockIdx.x * blockDim.x + threadIdx.x;
    if (v < N_NODES) dinv[v] = rsqrtf((float)degInt[v] + 1.0f);
}

// ---------- layer1 GEMM: h1hat = (x @ W1) * dinv, s1 seeded with self-loop term ----------
// block = 256 threads = 4 nodes x 64 outputs
__global__ void k_gemm1(const float* __restrict__ x,
                        const float* __restrict__ W1,
                        const float* __restrict__ dinv,
                        float* __restrict__ h1hat, float* __restrict__ s1) {
    __shared__ __align__(16) float xs[4][F_IN];
    int t = threadIdx.x;
    int node0 = blockIdx.x * 4;
    // stage 4 rows of x via float4 (128 float4 loads)
    const float4* x4 = (const float4*)x;
    if (t < 128) {
        int r = t >> 5, c4 = t & 31;
        int v = node0 + r;
        float4 val = (v < N_NODES) ? x4[v * (F_IN / 4) + c4]
                                   : make_float4(0.f, 0.f, 0.f, 0.f);
        ((float4*)xs[r])[c4] = val;
    }
    __syncthreads();
    int r = t >> 6;
    int j = t & 63;
    int v = node0 + r;
    if (v >= N_NODES) return;
    float acc = 0.f;
#pragma unroll 8
    for (int k = 0; k < F_IN; ++k)
        acc += xs[r][k] * W1[k * H1 + j];
    float val = acc * dinv[v];
    h1hat[v * H1 + j] = val;
    s1[v * H1 + j]    = val;  // self-loop seed
}

// ---------- edge scatter, 64 features ----------
__global__ void k_scatter64(const int* __restrict__ src, const int* __restrict__ dst,
                            const float* __restrict__ hhat, float* __restrict__ s) {
    long i = (long)blockIdx.x * blockDim.x + threadIdx.x;
    if (i >= (long)N_EDGES * 64) return;
    int e = (int)(i >> 6), j = (int)(i & 63);
    int sv = src[e], dv = dst[e];
    atomicAdd(&s[dv * 64 + j], hhat[sv * 64 + j]);
}

// ---------- finalize layer1 + GEMM2 ----------
__global__ void k_layer2(const float* __restrict__ s1, const float* __restrict__ dinv,
                         const float* __restrict__ b1,
                         const float* __restrict__ W2,
                         float* __restrict__ h2hat, float* __restrict__ s2) {
    __shared__ float h1s[4][H1];
    int t = threadIdx.x;
    int node0 = blockIdx.x * 4;
    int r = t >> 6, k = t & 63;
    int v = node0 + r;
    float dv_ = 0.f;
    if (v < N_NODES) {
        dv_ = dinv[v];
        float h = dv_ * s1[v * H1 + k] + b1[k];
        h1s[r][k] = fmaxf(h, 0.f);
    }
    __syncthreads();
    if (v < N_NODES && k < H2) {
        float acc = 0.f;
#pragma unroll 8
        for (int kk = 0; kk < H1; ++kk)
            acc += h1s[r][kk] * W2[kk * H2 + k];
        float val = acc * dv_;
        h2hat[v * H2 + k] = val;
        s2[v * H2 + k]    = val;  // self-loop seed
    }
}

// ---------- edge scatter, 32 features ----------
__global__ void k_scatter32(const int* __restrict__ src, const int* __restrict__ dst,
                            const float* __restrict__ hhat, float* __restrict__ s) {
    long i = (long)blockIdx.x * blockDim.x + threadIdx.x;
    if (i >= (long)N_EDGES * 32) return;
    int e = (int)(i >> 5), j = (int)(i & 31);
    int sv = src[e], dv = dst[e];
    atomicAdd(&s[dv * 32 + j], hhat[sv * 32 + j]);
}

// ---------- finalize layer2 + mean accumulate ----------
__global__ void k_mean(const float* __restrict__ s2, const float* __restrict__ dinv,
                       const float* __restrict__ b2, float* __restrict__ g) {
    __shared__ float red[256];
    int t = threadIdx.x;
    int r = t >> 5, j = t & 31;
    int v = blockIdx.x * 8 + r;
    float val = 0.f;
    if (v < N_NODES) {
        float dv_ = dinv[v];
        val = fmaxf(dv_ * s2[v * H2 + j] + b2[j], 0.f);
    }
    red[t] = val;
    __syncthreads();
    if (r == 0) {
        float sum = 0.f;
#pragma unroll
        for (int rr = 0; rr < 8; ++rr) sum += red[rr * 32 + j];
        atomicAdd(&g[j], sum);
    }
}

// ---------- final FC ----------
__global__ void k_out(const float* __restrict__ g,
                      const float* __restrict__ Wfc,
                      const float* __restrict__ bfc,
                      float* __restrict__ out) {
    int c = threadIdx.x;
    if (c < N_CLASSES) {
        float acc = 0.f;
#pragma unroll
        for (int j = 0; j < H2; ++j)
            acc += g[j] * Wfc[j * N_CLASSES + c];
        float invN = 1.0f / (float)N_NODES;
        out[c] = acc * invN + bfc[c];
    }
}

extern "C" void kernel_launch(void* const* d_in, const int* in_sizes, int n_in,
                              void* d_out, int out_size, void* d_ws, size_t ws_size,
                              hipStream_t stream) {
    const float* x   = (const float*)d_in[0];
    const float* W1  = (const float*)d_in[1];
    const float* b1  = (const float*)d_in[2];
    const float* W2  = (const float*)d_in[3];
    const float* b2  = (const float*)d_in[4];
    const float* Wfc = (const float*)d_in[5];
    const float* bfc = (const float*)d_in[6];
    const int* edge = (const int*)d_in[7];
    const int* srcI = edge;              // edge_index[0]
    const int* dstI = edge + N_EDGES;    // edge_index[1]
    float* out = (float*)d_out;

    // workspace layout (fp32 intermediates)
    char* ws = (char*)d_ws;
    int*   degInt = (int*)  (ws + 0);                           // 10000 ints
    float* dinv   = (float*)(ws + 40960);                       // 10000 f
    float* h1hat  = (float*)(ws + 81920);                       // 640000 f
    float* s1     = (float*)(ws + 81920 + 2560000);             // 640000 f
    float* h2hat  = (float*)(ws + 81920 + 2*2560000);           // 320000 f
    float* s2     = (float*)(ws + 81920 + 2*2560000 + 1280000); // 320000 f
    float* g      = (float*)(ws + 81920 + 2*2560000 + 2*1280000); // 32 f

    hipMemsetAsync(degInt, 0, N_NODES * sizeof(int), stream);
    hipMemsetAsync(g, 0, H2 * sizeof(float), stream);

    k_deg<<<(N_EDGES + 255) / 256, 256, 0, stream>>>(dstI, degInt);
    k_dinv<<<(N_NODES + 255) / 256, 256, 0, stream>>>(degInt, dinv);
    k_gemm1<<<(N_NODES + 3) / 4, 256, 0, stream>>>(x, W1, dinv, h1hat, s1);
    {
        long total = (long)N_EDGES * 64;
        k_scatter64<<<(int)((total + 255) / 256), 256, 0, stream>>>(srcI, dstI, h1hat, s1);
    }
    k_layer2<<<(N_NODES + 3) / 4, 256, 0, stream>>>(s1, dinv, b1, W2, h2hat, s2);
    {
        long total = (long)N_EDGES * 32;
        k_scatter32<<<(int)((total + 255) / 256), 256, 0, stream>>>(srcI, dstI, h2hat, s2);
    }
    k_mean<<<(N_NODES + 7) / 8, 256, 0, stream>>>(s2, dinv, b2, g);
    k_out<<<1, 64, 0, stream>>>(g, Wfc, bfc, out);
}

// Round 3
// 243.536 us; speedup vs baseline: 1.5011x; 1.5011x over previous
//
#include <hip/hip_runtime.h>

#define N_NODES 10000
#define N_EDGES 640000
#define F_IN 128
#define H1 64
#define H2 32
#define N_CLASSES 16

// ---------- degree count ----------
__global__ void k_deg(const int* __restrict__ dst, int* __restrict__ degInt) {
    int e = blockIdx.x * blockDim.x + threadIdx.x;
    if (e < N_EDGES) atomicAdd(&degInt[dst[e]], 1);
}

// ---------- one-block scan: rowStart (exclusive), cursor copy, dinv ----------
__global__ void __launch_bounds__(1024) k_scan(const int* __restrict__ degInt,
                                               float* __restrict__ dinv,
                                               int* __restrict__ rowStart,
                                               int* __restrict__ cursor) {
    __shared__ int part[1024];
    const int CH = 10;  // 1024 * 10 = 10240 >= N_NODES
    int t = threadIdx.x;
    int base = t * CH;
    int deg[CH];
    int s = 0;
    for (int i = 0; i < CH; ++i) {
        int idx = base + i;
        deg[i] = (idx < N_NODES) ? degInt[idx] : 0;
        s += deg[i];
    }
    part[t] = s;
    __syncthreads();
    // Hillis-Steele inclusive scan over 1024 partials (10 steps)
    for (int off = 1; off < 1024; off <<= 1) {
        int v = (t >= off) ? part[t - off] : 0;
        __syncthreads();
        part[t] += v;
        __syncthreads();
    }
    int ex = part[t] - s;  // exclusive prefix for this chunk
    for (int i = 0; i < CH; ++i) {
        int idx = base + i;
        if (idx < N_NODES) {
            rowStart[idx] = ex;
            cursor[idx]   = ex;
            dinv[idx]     = rsqrtf((float)deg[i] + 1.0f);
            ex += deg[i];
        }
    }
    if (t == 1023) rowStart[N_NODES] = part[1023];
}

// ---------- counting-sort fill: srcSorted grouped by dst ----------
__global__ void k_fill(const int* __restrict__ src, const int* __restrict__ dst,
                       int* __restrict__ cursor, int* __restrict__ srcSorted) {
    int e = blockIdx.x * blockDim.x + threadIdx.x;
    if (e < N_EDGES) {
        int pos = atomicAdd(&cursor[dst[e]], 1);
        srcSorted[pos] = src[e];
    }
}

// ---------- layer1 GEMM: h1hat = (x @ W1) * dinv ----------
// block = 256 threads = 4 nodes x 64 outputs
__global__ void k_gemm1(const float* __restrict__ x,
                        const float* __restrict__ W1,
                        const float* __restrict__ dinv,
                        float* __restrict__ h1hat) {
    __shared__ __align__(16) float xs[4][F_IN];
    int t = threadIdx.x;
    int node0 = blockIdx.x * 4;
    const float4* x4 = (const float4*)x;
    if (t < 128) {
        int r = t >> 5, c4 = t & 31;
        int v = node0 + r;
        float4 val = (v < N_NODES) ? x4[v * (F_IN / 4) + c4]
                                   : make_float4(0.f, 0.f, 0.f, 0.f);
        ((float4*)xs[r])[c4] = val;
    }
    __syncthreads();
    int r = t >> 6;
    int j = t & 63;
    int v = node0 + r;
    if (v >= N_NODES) return;
    float acc = 0.f;
#pragma unroll 8
    for (int k = 0; k < F_IN; ++k)
        acc += xs[r][k] * W1[k * H1 + j];
    h1hat[v * H1 + j] = acc * dinv[v];
}

// ---------- gather layer1 (CSR) + ReLU + GEMM2 + dinv-scale ----------
// block = 256 = 4 waves; wave w owns node v, lane j = feature of h1
__global__ void k_gather1_gemm2(const float* __restrict__ h1hat,
                                const int* __restrict__ rowStart,
                                const int* __restrict__ srcSorted,
                                const float* __restrict__ dinv,
                                const float* __restrict__ b1,
                                const float* __restrict__ W2,
                                float* __restrict__ h2hat) {
    __shared__ float h1s[4][H1];
    int t = threadIdx.x;
    int w = t >> 6, j = t & 63;
    int v = blockIdx.x * 4 + w;
    float dv_ = 0.f;
    if (v < N_NODES) {
        dv_ = dinv[v];
        int rs = rowStart[v], re = rowStart[v + 1];
        float sum = h1hat[v * H1 + j];  // self-loop term
        float s0 = 0.f, s1 = 0.f, s2 = 0.f, s3 = 0.f;
        int e = rs;
        for (; e + 4 <= re; e += 4) {
            int a0 = srcSorted[e], a1 = srcSorted[e + 1];
            int a2 = srcSorted[e + 2], a3 = srcSorted[e + 3];
            s0 += h1hat[a0 * H1 + j];
            s1 += h1hat[a1 * H1 + j];
            s2 += h1hat[a2 * H1 + j];
            s3 += h1hat[a3 * H1 + j];
        }
        for (; e < re; ++e) sum += h1hat[srcSorted[e] * H1 + j];
        sum += (s0 + s1) + (s2 + s3);
        h1s[w][j] = fmaxf(dv_ * sum + b1[j], 0.f);  // h1 (post-ReLU)
    }
    __syncthreads();
    if (v < N_NODES && j < H2) {
        float acc = 0.f;
#pragma unroll
        for (int kk = 0; kk < H1; ++kk)
            acc += h1s[w][kk] * W2[kk * H2 + j];
        h2hat[v * H2 + j] = acc * dv_;  // pre-scaled for layer-2 aggregation
    }
}

// ---------- gather layer2 (CSR) + ReLU + block mean reduce ----------
// block = 256 = 8 nodes x 32 features (half-wave per node)
__global__ void k_gather2_mean(const float* __restrict__ h2hat,
                               const int* __restrict__ rowStart,
                               const int* __restrict__ srcSorted,
                               const float* __restrict__ dinv,
                               const float* __restrict__ b2,
                               float* __restrict__ g) {
    __shared__ float red[256];
    int t = threadIdx.x;
    int slot = t >> 5;  // 0..7
    int j = t & 31;
    int v = blockIdx.x * 8 + slot;
    float val = 0.f;
    if (v < N_NODES) {
        float dv_ = dinv[v];
        int rs = rowStart[v], re = rowStart[v + 1];
        float sum = h2hat[v * H2 + j];  // self-loop term
        float s0 = 0.f, s1 = 0.f;
        int e = rs;
        for (; e + 2 <= re; e += 2) {
            int a0 = srcSorted[e], a1 = srcSorted[e + 1];
            s0 += h2hat[a0 * H2 + j];
            s1 += h2hat[a1 * H2 + j];
        }
        for (; e < re; ++e) sum += h2hat[srcSorted[e] * H2 + j];
        sum += s0 + s1;
        val = fmaxf(dv_ * sum + b2[j], 0.f);
    }
    red[t] = val;
    __syncthreads();
    if (t < 32) {
        float s = 0.f;
#pragma unroll
        for (int r = 0; r < 8; ++r) s += red[r * 32 + t];
        atomicAdd(&g[t], s);
    }
}

// ---------- final FC ----------
__global__ void k_out(const float* __restrict__ g,
                      const float* __restrict__ Wfc,
                      const float* __restrict__ bfc,
                      float* __restrict__ out) {
    int c = threadIdx.x;
    if (c < N_CLASSES) {
        float acc = 0.f;
#pragma unroll
        for (int j = 0; j < H2; ++j)
            acc += g[j] * Wfc[j * N_CLASSES + c];
        float invN = 1.0f / (float)N_NODES;
        out[c] = acc * invN + bfc[c];
    }
}

extern "C" void kernel_launch(void* const* d_in, const int* in_sizes, int n_in,
                              void* d_out, int out_size, void* d_ws, size_t ws_size,
                              hipStream_t stream) {
    const float* x   = (const float*)d_in[0];
    const float* W1  = (const float*)d_in[1];
    const float* b1  = (const float*)d_in[2];
    const float* W2  = (const float*)d_in[3];
    const float* b2  = (const float*)d_in[4];
    const float* Wfc = (const float*)d_in[5];
    const float* bfc = (const float*)d_in[6];
    const int* edge = (const int*)d_in[7];
    const int* srcI = edge;              // edge_index[0]
    const int* dstI = edge + N_EDGES;    // edge_index[1]
    float* out = (float*)d_out;

    // workspace layout
    char* ws = (char*)d_ws;
    int*   degInt    = (int*)  (ws + 0);        // 10000 ints
    float* dinv      = (float*)(ws + 40960);    // 10000 f
    int*   rowStart  = (int*)  (ws + 81920);    // 10001 ints
    int*   cursor    = (int*)  (ws + 122880);   // 10000 ints
    int*   srcSorted = (int*)  (ws + 163840);   // 640000 ints
    float* h1hat     = (float*)(ws + 163840 + 2560000);            // 640000 f
    float* h2hat     = (float*)(ws + 163840 + 2 * 2560000);        // 320000 f
    float* g         = (float*)(ws + 163840 + 2 * 2560000 + 1280000); // 32 f

    hipMemsetAsync(degInt, 0, N_NODES * sizeof(int), stream);
    hipMemsetAsync(g, 0, H2 * sizeof(float), stream);

    k_deg<<<(N_EDGES + 255) / 256, 256, 0, stream>>>(dstI, degInt);
    k_scan<<<1, 1024, 0, stream>>>(degInt, dinv, rowStart, cursor);
    k_fill<<<(N_EDGES + 255) / 256, 256, 0, stream>>>(srcI, dstI, cursor, srcSorted);
    k_gemm1<<<(N_NODES + 3) / 4, 256, 0, stream>>>(x, W1, dinv, h1hat);
    k_gather1_gemm2<<<(N_NODES + 3) / 4, 256, 0, stream>>>(h1hat, rowStart, srcSorted,
                                                           dinv, b1, W2, h2hat);
    k_gather2_mean<<<(N_NODES + 7) / 8, 256, 0, stream>>>(h2hat, rowStart, srcSorted,
                                                          dinv, b2, g);
    k_out<<<1, 64, 0, stream>>>(g, Wfc, bfc, out);
}